// Round 4
// baseline (6040.413 us; speedup 1.0000x reference)
//
#include <hip/hip_runtime.h>
#include <hip/hip_fp16.h>

typedef _Float16 f16x8 __attribute__((ext_vector_type(8)));
typedef float f32x4 __attribute__((ext_vector_type(4)));

#define TT 512
#define HH 512
#define BB 64

// ws layout (bytes)
#define WS_FLAGS 0            // int[2][4][32] = 1 KB (memset to 0 each launch)
#define WS_LENS  4096         // int[64]
#define WS_HBUF  8192         // fp16 [dir][parity][64][512] = 262144 B  (ends ~270 KB)

#define MFMA(a, b, c) __builtin_amdgcn_mfma_f32_16x16x32_f16((a), (b), (c), 0, 0, 0)

__device__ __forceinline__ float fsig(float x) {
  float ax = __builtin_fabsf(x);
  float t  = __builtin_amdgcn_exp2f(-1.442695041f * ax);   // e^{-|x|}
  float r  = __builtin_amdgcn_rcpf(1.0f + t);
  return x >= 0.0f ? r : t * r;                            // sigmoid(x)
}
__device__ __forceinline__ float ftanh_(float x) {
  float ax = __builtin_fabsf(x);
  float t  = __builtin_amdgcn_exp2f(-2.885390082f * ax);   // e^{-2|x|}
  float r  = (1.0f - t) * __builtin_amdgcn_rcpf(1.0f + t); // tanh(|x|)
  return x >= 0.0f ? r : -r;
}

__global__ void len_kernel(const float* __restrict__ mask, int* __restrict__ lens) {
  int b = threadIdx.x;
  if (b < BB) {
    float s = 0.f;
    for (int t = 0; t < TT; ++t) s += mask[b * TT + t];
    lens[b] = (int)(s + 0.5f);
  }
}

// 256 blocks: bid = dir*128 + bg*32 + cg
//   dir in {0,1}; bg in [0,4): batches [bg*16, bg*16+16); cg in [0,32): h-cols [cg*16, cg*16+16)
// Each block computes gates[16 batches x 64 gate-cols] per step (64 gate-cols = 4 gates x 16 h-cols).
// Wave wv (0..3) = gate type wv; lane&15 = batch row (MFMA M) for A / gate col for B; lane>>4 = k-group.
// Co-residency: __launch_bounds__(256,1) + ~300 VGPR -> exactly 1 block/CU; grid 256 = CU count.
__global__ void __launch_bounds__(256, 1)
bilstm_kernel(const float* __restrict__ x, const int* __restrict__ lens,
              const float* __restrict__ h0, const float* __restrict__ c0,
              const float* __restrict__ Wi_f, const float* __restrict__ Wh_f,
              const float* __restrict__ b_f,
              const float* __restrict__ Wi_b, const float* __restrict__ Wh_b,
              const float* __restrict__ b_b,
              float* __restrict__ out, __half* hbuf, int* flags)
{
  const int bid = blockIdx.x;
  const int dir = bid >> 7;
  const int bg  = (bid >> 5) & 3;
  const int cg  = bid & 31;
  const int tid = threadIdx.x;
  const int wv  = tid >> 6;
  const int ln  = tid & 63;
  const int il  = ln & 15;   // MFMA M/N index
  const int kg  = ln >> 4;   // k-group 0..3

  const float* Wi = dir ? Wi_b : Wi_f;
  const float* Wh = dir ? Wh_b : Wh_f;
  const float* bv = dir ? b_b  : b_f;

  __half* hb = hbuf + (size_t)dir * (2 * BB * HH);   // [parity][64][512]
  int* fl = flags + (dir * 4 + bg) * 32;             // one flag per col-group

  __shared__ float glds[16][68];                      // gates bounce [b_local][gate*16+i]

  // ---- stationary weights -> registers (B-frags: lane holds Wcat[col][k0..k0+7]) ----
  const int jrow = wv * HH + cg * 16 + il;            // global gate row
  f16x8 wreg[32];
#pragma unroll
  for (int kk = 0; kk < 32; ++kk) {
    int k0 = kk * 32 + kg * 8;
    const float* src = (k0 < 512) ? (Wi + (size_t)jrow * 512 + k0)
                                  : (Wh + (size_t)jrow * 512 + (k0 - 512));
    float4 f0 = *(const float4*)(src);
    float4 f1 = *(const float4*)(src + 4);
    f16x8 w;
    w[0] = (_Float16)f0.x; w[1] = (_Float16)f0.y; w[2] = (_Float16)f0.z; w[3] = (_Float16)f0.w;
    w[4] = (_Float16)f1.x; w[5] = (_Float16)f1.y; w[6] = (_Float16)f1.z; w[7] = (_Float16)f1.w;
    wreg[kk] = w;
  }

  // ---- elementwise role: thread tid <-> (b_local = tid>>4, i = tid&15) ----
  const int bl_e  = tid >> 4;
  const int i_e   = tid & 15;
  const int b_e   = bg * 16 + bl_e;
  const int col_e = cg * 16 + i_e;
  float cst = c0[(size_t)b_e * HH + col_e];
  const float bi_ = bv[0 * HH + col_e];
  const float bf_ = bv[1 * HH + col_e];
  const float bg_ = bv[2 * HH + col_e];
  const float bo_ = bv[3 * HH + col_e];
  const int len_e = lens[b_e];

  // ---- gemm role: A-frag row = batch ----
  const int b_g   = bg * 16 + il;
  const int len_b = lens[b_g];

  // ---- init h(-1) (parity 1) from h0, LLC-coherent ----
  {
    unsigned short hbits = __half_as_ushort(__float2half(h0[(size_t)b_e * HH + col_e]));
    unsigned short* p = (unsigned short*)(hb + (size_t)1 * BB * HH + (size_t)b_e * HH + col_e);
    __hip_atomic_store(p, hbits, __ATOMIC_RELAXED, __HIP_MEMORY_SCOPE_AGENT);
  }
  __syncthreads();  // barrier drains vmcnt -> init stores are at LLC
  if (tid == 0)
    __hip_atomic_store(&fl[cg], 1, __ATOMIC_RELAXED, __HIP_MEMORY_SCOPE_AGENT);

  for (int t = 0; t < TT; ++t) {
    // ---- x A-frags for this step: f32 load + in-register f16 convert ----
    // (independent of h; issued before the spin so latency hides under sync)
    int tsrc;
    if (dir == 0) tsrc = t;
    else { int v = len_b + (TT - 1) - t; if (v >= TT) v -= TT; tsrc = v; }
    const float* xrow = x + ((size_t)b_g * TT + tsrc) * 512;
    f16x8 ax[16];
#pragma unroll
    for (int kk = 0; kk < 16; ++kk) {
      float4 f0 = *(const float4*)(xrow + kk * 32 + kg * 8);
      float4 f1 = *(const float4*)(xrow + kk * 32 + kg * 8 + 4);
      f16x8 w;
      w[0] = (_Float16)f0.x; w[1] = (_Float16)f0.y; w[2] = (_Float16)f0.z; w[3] = (_Float16)f0.w;
      w[4] = (_Float16)f1.x; w[5] = (_Float16)f1.y; w[6] = (_Float16)f1.z; w[7] = (_Float16)f1.w;
      ax[kk] = w;
    }

    // ---- wait until all 32 blocks of this (dir,bg) group published h(t-1) ----
    if (wv == 0) {
      const int need = t + 1;
      while (1) {
        int v = __hip_atomic_load(&fl[ln & 31], __ATOMIC_RELAXED, __HIP_MEMORY_SCOPE_AGENT);
        if (__all(v >= need)) break;
        __builtin_amdgcn_s_sleep(1);
      }
    }
    __syncthreads();

    // ---- h A-frags (LLC-coherent relaxed atomic loads; bypass stale per-XCD L2) ----
    const __half* hrow = hb + (size_t)((t + 1) & 1) * BB * HH + (size_t)b_g * HH;
    uint4 ah[16];
#pragma unroll
    for (int kk = 0; kk < 16; ++kk) {
      const unsigned int* p = (const unsigned int*)(hrow + kk * 32 + kg * 8);
      uint4 v;
      v.x = __hip_atomic_load(p + 0, __ATOMIC_RELAXED, __HIP_MEMORY_SCOPE_AGENT);
      v.y = __hip_atomic_load(p + 1, __ATOMIC_RELAXED, __HIP_MEMORY_SCOPE_AGENT);
      v.z = __hip_atomic_load(p + 2, __ATOMIC_RELAXED, __HIP_MEMORY_SCOPE_AGENT);
      v.w = __hip_atomic_load(p + 3, __ATOMIC_RELAXED, __HIP_MEMORY_SCOPE_AGENT);
      ah[kk] = v;
    }

    // ---- gates = [x_t; h_{t-1}] @ Wcat^T  (4 indep accum chains) ----
    f32x4 ac0 = {0.f,0.f,0.f,0.f}, ac1 = {0.f,0.f,0.f,0.f};
    f32x4 ac2 = {0.f,0.f,0.f,0.f}, ac3 = {0.f,0.f,0.f,0.f};
#pragma unroll
    for (int kk = 0; kk < 16; kk += 4) {
      ac0 = MFMA(ax[kk + 0], wreg[kk + 0], ac0);
      ac1 = MFMA(ax[kk + 1], wreg[kk + 1], ac1);
      ac2 = MFMA(ax[kk + 2], wreg[kk + 2], ac2);
      ac3 = MFMA(ax[kk + 3], wreg[kk + 3], ac3);
    }
#pragma unroll
    for (int kk = 0; kk < 16; kk += 4) {
      ac0 = MFMA(__builtin_bit_cast(f16x8, ah[kk + 0]), wreg[16 + kk + 0], ac0);
      ac1 = MFMA(__builtin_bit_cast(f16x8, ah[kk + 1]), wreg[16 + kk + 1], ac1);
      ac2 = MFMA(__builtin_bit_cast(f16x8, ah[kk + 2]), wreg[16 + kk + 2], ac2);
      ac3 = MFMA(__builtin_bit_cast(f16x8, ah[kk + 3]), wreg[16 + kk + 3], ac3);
    }

    // D-frag: col = lane&15, row = (lane>>4)*4 + r  (m89-verified, dtype-independent)
#pragma unroll
    for (int r = 0; r < 4; ++r)
      glds[kg * 4 + r][wv * 16 + il] = ac0[r] + ac1[r] + ac2[r] + ac3[r];
    __syncthreads();

    // ---- LSTM cell (gate order i,f,g,o) ----
    float gi = glds[bl_e][ 0 + i_e] + bi_;
    float gf = glds[bl_e][16 + i_e] + bf_;
    float gg = glds[bl_e][32 + i_e] + bg_;
    float go = glds[bl_e][48 + i_e] + bo_;
    float si = fsig(gi), sf = fsig(gf), so = fsig(go);
    float tg = ftanh_(gg);
    cst = sf * cst + si * tg;
    float hv = so * ftanh_(cst);

    // publish h(t) (parity t&1), LLC-coherent
    unsigned short hbits = __half_as_ushort(__float2half(hv));
    unsigned short* hp = (unsigned short*)(hb + (size_t)(t & 1) * BB * HH + (size_t)b_e * HH + col_e);
    __hip_atomic_store(hp, hbits, __ATOMIC_RELAXED, __HIP_MEMORY_SCOPE_AGENT);

    // output write: fwd -> [b][t][col]; bwd -> [b][(len-1-t) mod T][H+col]
    if (dir == 0) {
      out[((size_t)b_e * TT + t) * (2 * HH) + col_e] = hv;
    } else {
      int td = len_e - 1 - t; if (td < 0) td += TT;
      out[((size_t)b_e * TT + td) * (2 * HH) + HH + col_e] = hv;
    }

    __syncthreads();  // drains all threads' stores (vmcnt 0) before the flag release
    if (tid == 0)
      __hip_atomic_store(&fl[cg], t + 2, __ATOMIC_RELAXED, __HIP_MEMORY_SCOPE_AGENT);
  }
}

extern "C" void kernel_launch(void* const* d_in, const int* in_sizes, int n_in,
                              void* d_out, int out_size, void* d_ws, size_t ws_size,
                              hipStream_t stream) {
  const float* x    = (const float*)d_in[0];
  const float* mask = (const float*)d_in[1];
  const float* h0   = (const float*)d_in[2];
  const float* c0   = (const float*)d_in[3];
  const float* Wi_f = (const float*)d_in[4];
  const float* Wh_f = (const float*)d_in[5];
  const float* b_f  = (const float*)d_in[6];
  const float* Wi_b = (const float*)d_in[7];
  const float* Wh_b = (const float*)d_in[8];
  const float* b_b  = (const float*)d_in[9];
  float* out = (float*)d_out;

  char* ws = (char*)d_ws;
  int*    flags = (int*)(ws + WS_FLAGS);
  int*    lens  = (int*)(ws + WS_LENS);
  __half* hbuf  = (__half*)(ws + WS_HBUF);

  // zero the sync flags every call (harness poisons ws once with 0xAA)
  hipMemsetAsync(ws, 0, 4096, stream);

  hipLaunchKernelGGL(len_kernel, dim3(1), dim3(64), 0, stream, mask, lens);

  // Plain (non-cooperative) launch: 1 block/CU by construction, grid == CU count,
  // so all 256 blocks are co-resident at dispatch; sync is hand-rolled flags.
  hipLaunchKernelGGL(bilstm_kernel, dim3(256), dim3(256), 0, stream,
                     x, lens, h0, c0, Wi_f, Wh_f, b_f, Wi_b, Wh_b, b_b,
                     out, hbuf, flags);
}

// Round 5
// 5979.350 us; speedup vs baseline: 1.0102x; 1.0102x over previous
//
#include <hip/hip_runtime.h>
#include <hip/hip_fp16.h>

typedef _Float16 f16x8 __attribute__((ext_vector_type(8)));
typedef float f32x4 __attribute__((ext_vector_type(4)));

#define TT 512
#define HH 512
#define BB 64

// ws layout (bytes)
#define WS_FLAGS 0            // int[2][4][32] = 1 KB (memset to 0 each launch)
#define WS_LENS  4096         // int[64]
#define WS_HBUF  8192         // fp16 [dir][parity][64][512] = 262144 B  (ends ~270 KB)

// dynamic LDS layout (bytes)
#define LDS_W     0            // f16x8 [4 waves][32 k-slices][64 lanes] = 131072 B
#define LDS_GLDS  131072       // float [16][68] = 4352 B
#define LDS_TOTAL 135424

#define MFMA(a, b, c) __builtin_amdgcn_mfma_f32_16x16x32_f16((a), (b), (c), 0, 0, 0)

__device__ __forceinline__ float fsig(float x) {
  float ax = __builtin_fabsf(x);
  float t  = __builtin_amdgcn_exp2f(-1.442695041f * ax);   // e^{-|x|}
  float r  = __builtin_amdgcn_rcpf(1.0f + t);
  return x >= 0.0f ? r : t * r;                            // sigmoid(x)
}
__device__ __forceinline__ float ftanh_(float x) {
  float ax = __builtin_fabsf(x);
  float t  = __builtin_amdgcn_exp2f(-2.885390082f * ax);   // e^{-2|x|}
  float r  = (1.0f - t) * __builtin_amdgcn_rcpf(1.0f + t); // tanh(|x|)
  return x >= 0.0f ? r : -r;
}

__global__ void len_kernel(const float* __restrict__ mask, int* __restrict__ lens) {
  int b = threadIdx.x;
  if (b < BB) {
    float s = 0.f;
    for (int t = 0; t < TT; ++t) s += mask[b * TT + t];
    lens[b] = (int)(s + 0.5f);
  }
}

// 256 blocks: bid = dir*128 + bg*32 + cg
//   dir in {0,1}; bg in [0,4): batches [bg*16, bg*16+16); cg in [0,32): h-cols [cg*16, cg*16+16)
// Each block computes gates[16 batches x 64 gate-cols] per step (64 gate-cols = 4 gates x 16 h-cols).
// Wave wv (0..3) = gate type wv; lane&15 = MFMA M/N; lane>>4 = k-group.
// Weights: f16 in LDS (128 KB/block) -- structurally resident, allocator can't remat them.
// Co-residency: 135 KB LDS -> exactly 1 block/CU; grid 256 = CU count.
__global__ void __launch_bounds__(256, 1)
bilstm_kernel(const float* __restrict__ x, const int* __restrict__ lens,
              const float* __restrict__ h0, const float* __restrict__ c0,
              const float* __restrict__ Wi_f, const float* __restrict__ Wh_f,
              const float* __restrict__ b_f,
              const float* __restrict__ Wi_b, const float* __restrict__ Wh_b,
              const float* __restrict__ b_b,
              float* __restrict__ out, __half* hbuf, int* flags)
{
  extern __shared__ __align__(16) char smem[];
  f16x8* wlds = (f16x8*)(smem + LDS_W);                 // [wv*32 + kk][ln]
  float (*glds)[68] = (float (*)[68])(smem + LDS_GLDS); // gates bounce [b_local][gate*16+i]

  const int bid = blockIdx.x;
  const int dir = bid >> 7;
  const int bg  = (bid >> 5) & 3;
  const int cg  = bid & 31;
  const int tid = threadIdx.x;
  const int wv  = tid >> 6;
  const int ln  = tid & 63;
  const int il  = ln & 15;   // MFMA M/N index
  const int kg  = ln >> 4;   // k-group 0..3

  const float* Wi = dir ? Wi_b : Wi_f;
  const float* Wh = dir ? Wh_b : Wh_f;
  const float* bv = dir ? b_b  : b_f;

  __half* hb = hbuf + (size_t)dir * (2 * BB * HH);   // [parity][64][512]
  int* fl = flags + (dir * 4 + bg) * 32;             // one flag per col-group

  // ---- stationary weights -> LDS, f16 (each lane fills its own B-frag slots) ----
  const int jrow = wv * HH + cg * 16 + il;            // global gate row
#pragma unroll 4
  for (int kk = 0; kk < 32; ++kk) {
    int k0 = kk * 32 + kg * 8;
    const float* src = (k0 < 512) ? (Wi + (size_t)jrow * 512 + k0)
                                  : (Wh + (size_t)jrow * 512 + (k0 - 512));
    float4 f0 = *(const float4*)(src);
    float4 f1 = *(const float4*)(src + 4);
    f16x8 w;
    w[0] = (_Float16)f0.x; w[1] = (_Float16)f0.y; w[2] = (_Float16)f0.z; w[3] = (_Float16)f0.w;
    w[4] = (_Float16)f1.x; w[5] = (_Float16)f1.y; w[6] = (_Float16)f1.z; w[7] = (_Float16)f1.w;
    wlds[(wv * 32 + kk) * 64 + ln] = w;
  }
  const f16x8* wbase = wlds + (size_t)wv * 32 * 64 + ln;  // wbase[kk*64] = this lane's B-frag kk

  // ---- elementwise role: thread tid <-> (b_local = tid>>4, i = tid&15) ----
  const int bl_e  = tid >> 4;
  const int i_e   = tid & 15;
  const int b_e   = bg * 16 + bl_e;
  const int col_e = cg * 16 + i_e;
  float cst = c0[(size_t)b_e * HH + col_e];
  const float bi_ = bv[0 * HH + col_e];
  const float bf_ = bv[1 * HH + col_e];
  const float bg_ = bv[2 * HH + col_e];
  const float bo_ = bv[3 * HH + col_e];
  const int len_e = lens[b_e];

  // ---- gemm role: A-frag row = batch ----
  const int b_g   = bg * 16 + il;
  const int len_b = lens[b_g];

  // ---- init h(-1) (parity 1) from h0, LLC-coherent ----
  {
    unsigned short hbits = __half_as_ushort(__float2half(h0[(size_t)b_e * HH + col_e]));
    unsigned short* p = (unsigned short*)(hb + (size_t)1 * BB * HH + (size_t)b_e * HH + col_e);
    __hip_atomic_store(p, hbits, __ATOMIC_RELAXED, __HIP_MEMORY_SCOPE_AGENT);
  }
  __syncthreads();  // drains vmcnt (init stores at LLC) + LDS weight fill visible
  if (tid == 0)
    __hip_atomic_store(&fl[cg], 1, __ATOMIC_RELAXED, __HIP_MEMORY_SCOPE_AGENT);

  for (int t = 0; t < TT; ++t) {
    // ---- x A-frags for this step: f32 load + in-register f16 convert ----
    // (independent of h; issued before the spin so latency hides under sync)
    int tsrc;
    if (dir == 0) tsrc = t;
    else { int v = len_b + (TT - 1) - t; if (v >= TT) v -= TT; tsrc = v; }
    const float* xrow = x + ((size_t)b_g * TT + tsrc) * 512;
    f16x8 ax[16];
#pragma unroll
    for (int kk = 0; kk < 16; ++kk) {
      float4 f0 = *(const float4*)(xrow + kk * 32 + kg * 8);
      float4 f1 = *(const float4*)(xrow + kk * 32 + kg * 8 + 4);
      f16x8 w;
      w[0] = (_Float16)f0.x; w[1] = (_Float16)f0.y; w[2] = (_Float16)f0.z; w[3] = (_Float16)f0.w;
      w[4] = (_Float16)f1.x; w[5] = (_Float16)f1.y; w[6] = (_Float16)f1.z; w[7] = (_Float16)f1.w;
      ax[kk] = w;
    }

    // ---- wait until all 32 blocks of this (dir,bg) group published h(t-1) ----
    if (wv == 0) {
      const int need = t + 1;
      while (1) {
        int v = __hip_atomic_load(&fl[ln & 31], __ATOMIC_RELAXED, __HIP_MEMORY_SCOPE_AGENT);
        if (__all(v >= need)) break;
        __builtin_amdgcn_s_sleep(1);
      }
    }
    __syncthreads();

    // ---- h A-frags (LLC-coherent relaxed atomic loads; bypass stale per-XCD L2) ----
    const __half* hrow = hb + (size_t)((t + 1) & 1) * BB * HH + (size_t)b_g * HH;
    uint4 ah[16];
#pragma unroll
    for (int kk = 0; kk < 16; ++kk) {
      const unsigned int* p = (const unsigned int*)(hrow + kk * 32 + kg * 8);
      uint4 v;
      v.x = __hip_atomic_load(p + 0, __ATOMIC_RELAXED, __HIP_MEMORY_SCOPE_AGENT);
      v.y = __hip_atomic_load(p + 1, __ATOMIC_RELAXED, __HIP_MEMORY_SCOPE_AGENT);
      v.z = __hip_atomic_load(p + 2, __ATOMIC_RELAXED, __HIP_MEMORY_SCOPE_AGENT);
      v.w = __hip_atomic_load(p + 3, __ATOMIC_RELAXED, __HIP_MEMORY_SCOPE_AGENT);
      ah[kk] = v;
    }

    // ---- gates = [x_t; h_{t-1}] @ Wcat^T  (4 indep accum chains; B-frags from LDS) ----
    // x MFMAs first: ax is ready, h loads still in flight underneath.
    f32x4 ac0 = {0.f,0.f,0.f,0.f}, ac1 = {0.f,0.f,0.f,0.f};
    f32x4 ac2 = {0.f,0.f,0.f,0.f}, ac3 = {0.f,0.f,0.f,0.f};
#pragma unroll
    for (int kk = 0; kk < 16; kk += 4) {
      ac0 = MFMA(ax[kk + 0], wbase[(kk + 0) * 64], ac0);
      ac1 = MFMA(ax[kk + 1], wbase[(kk + 1) * 64], ac1);
      ac2 = MFMA(ax[kk + 2], wbase[(kk + 2) * 64], ac2);
      ac3 = MFMA(ax[kk + 3], wbase[(kk + 3) * 64], ac3);
    }
#pragma unroll
    for (int kk = 0; kk < 16; kk += 4) {
      ac0 = MFMA(__builtin_bit_cast(f16x8, ah[kk + 0]), wbase[(16 + kk + 0) * 64], ac0);
      ac1 = MFMA(__builtin_bit_cast(f16x8, ah[kk + 1]), wbase[(16 + kk + 1) * 64], ac1);
      ac2 = MFMA(__builtin_bit_cast(f16x8, ah[kk + 2]), wbase[(16 + kk + 2) * 64], ac2);
      ac3 = MFMA(__builtin_bit_cast(f16x8, ah[kk + 3]), wbase[(16 + kk + 3) * 64], ac3);
    }

    // D-frag: col = lane&15, row = (lane>>4)*4 + r  (m89-verified, dtype-independent)
#pragma unroll
    for (int r = 0; r < 4; ++r)
      glds[kg * 4 + r][wv * 16 + il] = ac0[r] + ac1[r] + ac2[r] + ac3[r];
    __syncthreads();

    // ---- LSTM cell (gate order i,f,g,o) ----
    float gi = glds[bl_e][ 0 + i_e] + bi_;
    float gf = glds[bl_e][16 + i_e] + bf_;
    float gg = glds[bl_e][32 + i_e] + bg_;
    float go = glds[bl_e][48 + i_e] + bo_;
    float si = fsig(gi), sf = fsig(gf), so = fsig(go);
    float tg = ftanh_(gg);
    cst = sf * cst + si * tg;
    float hv = so * ftanh_(cst);

    // publish h(t) (parity t&1), LLC-coherent
    unsigned short hbits = __half_as_ushort(__float2half(hv));
    unsigned short* hp = (unsigned short*)(hb + (size_t)(t & 1) * BB * HH + (size_t)b_e * HH + col_e);
    __hip_atomic_store(hp, hbits, __ATOMIC_RELAXED, __HIP_MEMORY_SCOPE_AGENT);

    // output write: fwd -> [b][t][col]; bwd -> [b][(len-1-t) mod T][H+col]
    if (dir == 0) {
      out[((size_t)b_e * TT + t) * (2 * HH) + col_e] = hv;
    } else {
      int td = len_e - 1 - t; if (td < 0) td += TT;
      out[((size_t)b_e * TT + td) * (2 * HH) + HH + col_e] = hv;
    }

    __syncthreads();  // drains all threads' stores (vmcnt 0) before the flag release
    if (tid == 0)
      __hip_atomic_store(&fl[cg], t + 2, __ATOMIC_RELAXED, __HIP_MEMORY_SCOPE_AGENT);
  }
}

extern "C" void kernel_launch(void* const* d_in, const int* in_sizes, int n_in,
                              void* d_out, int out_size, void* d_ws, size_t ws_size,
                              hipStream_t stream) {
  const float* x    = (const float*)d_in[0];
  const float* mask = (const float*)d_in[1];
  const float* h0   = (const float*)d_in[2];
  const float* c0   = (const float*)d_in[3];
  const float* Wi_f = (const float*)d_in[4];
  const float* Wh_f = (const float*)d_in[5];
  const float* b_f  = (const float*)d_in[6];
  const float* Wi_b = (const float*)d_in[7];
  const float* Wh_b = (const float*)d_in[8];
  const float* b_b  = (const float*)d_in[9];
  float* out = (float*)d_out;

  char* ws = (char*)d_ws;
  int*    flags = (int*)(ws + WS_FLAGS);
  int*    lens  = (int*)(ws + WS_LENS);
  __half* hbuf  = (__half*)(ws + WS_HBUF);

  // zero the sync flags every call (harness poisons ws once with 0xAA)
  hipMemsetAsync(ws, 0, 4096, stream);

  hipLaunchKernelGGL(len_kernel, dim3(1), dim3(64), 0, stream, mask, lens);

  // opt-in to >64KB dynamic LDS (idempotent, not a stream op -> graph-capture safe)
  hipFuncSetAttribute((const void*)bilstm_kernel,
                      hipFuncAttributeMaxDynamicSharedMemorySize, LDS_TOTAL);

  // Plain (non-cooperative) launch: 135KB LDS -> 1 block/CU, grid == CU count,
  // so all 256 blocks are co-resident at dispatch; sync is hand-rolled flags.
  hipLaunchKernelGGL(bilstm_kernel, dim3(256), dim3(256), LDS_TOTAL, stream,
                     x, lens, h0, c0, Wi_f, Wh_f, b_f, Wi_b, Wh_b, b_b,
                     out, hbuf, flags);
}

// Round 6
// 2800.010 us; speedup vs baseline: 2.1573x; 2.1355x over previous
//
#include <hip/hip_runtime.h>
#include <hip/hip_fp16.h>

typedef _Float16 f16x8 __attribute__((ext_vector_type(8)));
typedef float f32x4 __attribute__((ext_vector_type(4)));

#define TT 512
#define HH 512
#define BB 64

// ws layout (bytes)
#define WS_FLAGS 0            // int[2][4][32] = 1 KB (memset to 0 each launch)
#define WS_LENS  4096         // int[64]
#define WS_HBUF  8192         // fp16 [dir][parity][64][512] = 262144 B  (ends ~270 KB)

// dynamic LDS layout (bytes)
#define LDS_W     0            // f16x8 [4 waves][32 k-slices][64 lanes] = 131072 B
#define LDS_GLDS  131072       // float [16][68] = 4352 B
#define LDS_H     135424       // f16 h-tile [16 rows][512 cols], XOR-swizzled = 16384 B
#define LDS_TOTAL 151808

#define MFMA(a, b, c) __builtin_amdgcn_mfma_f32_16x16x32_f16((a), (b), (c), 0, 0, 0)

__device__ __forceinline__ float fsig(float x) {
  float ax = __builtin_fabsf(x);
  float t  = __builtin_amdgcn_exp2f(-1.442695041f * ax);   // e^{-|x|}
  float r  = __builtin_amdgcn_rcpf(1.0f + t);
  return x >= 0.0f ? r : t * r;                            // sigmoid(x)
}
__device__ __forceinline__ float ftanh_(float x) {
  float ax = __builtin_fabsf(x);
  float t  = __builtin_amdgcn_exp2f(-2.885390082f * ax);   // e^{-2|x|}
  float r  = (1.0f - t) * __builtin_amdgcn_rcpf(1.0f + t); // tanh(|x|)
  return x >= 0.0f ? r : -r;
}

__global__ void len_kernel(const float* __restrict__ mask, int* __restrict__ lens) {
  int b = threadIdx.x;
  if (b < BB) {
    float s = 0.f;
    for (int t = 0; t < TT; ++t) s += mask[b * TT + t];
    lens[b] = (int)(s + 0.5f);
  }
}

// 256 blocks: bid = dir*128 + bg*32 + cg
//   dir in {0,1}; bg in [0,4): batches [bg*16, bg*16+16); cg in [0,32): h-cols [cg*16, cg*16+16)
// Each block computes gates[16 batches x 64 gate-cols] per step (64 gate-cols = 4 gates x 16 h-cols).
// Wave wv (0..3) = gate type wv; lane&15 = MFMA M/N; lane>>4 = k-group.
// h exchange: COALESCED 8B agent-atomic loads (once per block, not per wave) -> swizzled LDS tile
//   -> ds_read_b128 A-frags. This replaces 64 scattered 4B atomic loads/thread x 4-wave dup.
// Co-residency: 148 KB LDS -> exactly 1 block/CU; grid 256 = CU count.
__global__ void __launch_bounds__(256, 1)
bilstm_kernel(const float* __restrict__ x, const int* __restrict__ lens,
              const float* __restrict__ h0, const float* __restrict__ c0,
              const float* __restrict__ Wi_f, const float* __restrict__ Wh_f,
              const float* __restrict__ b_f,
              const float* __restrict__ Wi_b, const float* __restrict__ Wh_b,
              const float* __restrict__ b_b,
              float* __restrict__ out, __half* hbuf, int* flags)
{
  extern __shared__ __align__(16) char smem[];
  f16x8* wlds = (f16x8*)(smem + LDS_W);                 // [wv*32 + kk][ln]
  float (*glds)[68] = (float (*)[68])(smem + LDS_GLDS); // gates bounce [b_local][gate*16+i]
  char* htile = smem + LDS_H;                           // swizzled [16][1024B]

  const int bid = blockIdx.x;
  const int dir = bid >> 7;
  const int bg  = (bid >> 5) & 3;
  const int cg  = bid & 31;
  const int tid = threadIdx.x;
  const int wv  = tid >> 6;
  const int ln  = tid & 63;
  const int il  = ln & 15;   // MFMA M/N index
  const int kg  = ln >> 4;   // k-group 0..3

  const float* Wi = dir ? Wi_b : Wi_f;
  const float* Wh = dir ? Wh_b : Wh_f;
  const float* bv = dir ? b_b  : b_f;

  __half* hb = hbuf + (size_t)dir * (2 * BB * HH);   // [parity][64][512]
  int* fl = flags + (dir * 4 + bg) * 32;             // one flag per col-group

  // ---- stationary weights -> LDS, f16 (each lane fills its own B-frag slots) ----
  const int jrow = wv * HH + cg * 16 + il;            // global gate row
#pragma unroll 4
  for (int kk = 0; kk < 32; ++kk) {
    int k0 = kk * 32 + kg * 8;
    const float* src = (k0 < 512) ? (Wi + (size_t)jrow * 512 + k0)
                                  : (Wh + (size_t)jrow * 512 + (k0 - 512));
    float4 f0 = *(const float4*)(src);
    float4 f1 = *(const float4*)(src + 4);
    f16x8 w;
    w[0] = (_Float16)f0.x; w[1] = (_Float16)f0.y; w[2] = (_Float16)f0.z; w[3] = (_Float16)f0.w;
    w[4] = (_Float16)f1.x; w[5] = (_Float16)f1.y; w[6] = (_Float16)f1.z; w[7] = (_Float16)f1.w;
    wlds[(wv * 32 + kk) * 64 + ln] = w;
  }
  const f16x8* wbase = wlds + (size_t)wv * 32 * 64 + ln;  // wbase[kk*64] = this lane's B-frag kk

  // ---- elementwise role: thread tid <-> (b_local = tid>>4, i = tid&15) ----
  const int bl_e  = tid >> 4;
  const int i_e   = tid & 15;
  const int b_e   = bg * 16 + bl_e;
  const int col_e = cg * 16 + i_e;
  float cst = c0[(size_t)b_e * HH + col_e];
  const float bi_ = bv[0 * HH + col_e];
  const float bf_ = bv[1 * HH + col_e];
  const float bg_ = bv[2 * HH + col_e];
  const float bo_ = bv[3 * HH + col_e];
  const int len_e = lens[b_e];

  // ---- gemm role: A-frag row = batch ----
  const int b_g   = bg * 16 + il;
  const int len_b = lens[b_g];

  // ---- init h(-1) (parity 1) from h0, LLC-coherent ----
  {
    unsigned short hbits = __half_as_ushort(__float2half(h0[(size_t)b_e * HH + col_e]));
    unsigned short* p = (unsigned short*)(hb + (size_t)1 * BB * HH + (size_t)b_e * HH + col_e);
    __hip_atomic_store(p, hbits, __ATOMIC_RELAXED, __HIP_MEMORY_SCOPE_AGENT);
  }
  __syncthreads();  // drains vmcnt (init stores at LLC) + LDS weight fill visible
  if (tid == 0)
    __hip_atomic_store(&fl[cg], 1, __ATOMIC_RELAXED, __HIP_MEMORY_SCOPE_AGENT);

  // coalesced h source: this group's 16 rows are contiguous (16*512 f16 = 16 KB)
  const int hrbase = tid >> 7;          // 0 or 1 (row within 2-row sweep)
  const int hinrow = (tid & 127) * 8;   // byte offset within 1024B row

  for (int t = 0; t < TT; ++t) {
    // ---- x for this step: RAW f32 loads only (no cvt) before the spin, so the
    // 512B/lane stays in flight under the sync latency ----
    int tsrc;
    if (dir == 0) tsrc = t;
    else { int v = len_b + (TT - 1) - t; if (v >= TT) v -= TT; tsrc = v; }
    const float* xrow = x + ((size_t)b_g * TT + tsrc) * 512;
    float4 xr[32];
#pragma unroll
    for (int q = 0; q < 32; ++q)
      xr[q] = *(const float4*)(xrow + (q >> 1) * 32 + kg * 8 + (q & 1) * 4);

    // ---- all waves spin until the 32 col-group blocks published h(t-1) ----
    {
      const int need = t + 1;
      while (1) {
        int v = __hip_atomic_load(&fl[ln & 31], __ATOMIC_RELAXED, __HIP_MEMORY_SCOPE_AGENT);
        if (__all(v >= need)) break;
        __builtin_amdgcn_s_sleep(1);
      }
    }

    // ---- h(t-1): 8 coalesced 8B agent-atomic loads per thread (16 KB/block, once) ----
    const unsigned long long* hsrc = (const unsigned long long*)
        (hb + (size_t)((t + 1) & 1) * BB * HH + (size_t)bg * 16 * HH);
    unsigned long long hv64[8];
#pragma unroll
    for (int s = 0; s < 8; ++s)
      hv64[s] = __hip_atomic_load(hsrc + s * 256 + tid, __ATOMIC_RELAXED, __HIP_MEMORY_SCOPE_AGENT);

    // ---- convert x while the h loads are in flight ----
    f16x8 ax[16];
#pragma unroll
    for (int kk = 0; kk < 16; ++kk) {
      float4 f0 = xr[kk * 2], f1 = xr[kk * 2 + 1];
      f16x8 w;
      w[0] = (_Float16)f0.x; w[1] = (_Float16)f0.y; w[2] = (_Float16)f0.z; w[3] = (_Float16)f0.w;
      w[4] = (_Float16)f1.x; w[5] = (_Float16)f1.y; w[6] = (_Float16)f1.z; w[7] = (_Float16)f1.w;
      ax[kk] = w;
    }

    // ---- stage h into swizzled LDS tile (8B writes; XOR keeps 8B units intact) ----
#pragma unroll
    for (int s = 0; s < 8; ++s) {
      int row = s * 2 + hrbase;
      *(unsigned long long*)(htile + row * 1024 + (hinrow ^ ((row & 7) << 4))) = hv64[s];
    }
    __syncthreads();   // B2: htile ready (prior step's htile reads finished before last barrier)

    // ---- h A-frags: one ds_read_b128 per K-slice (swizzle matches the write) ----
    f16x8 fh[16];
#pragma unroll
    for (int kk = 0; kk < 16; ++kk) {
      int inr = kk * 64 + kg * 16;
      fh[kk] = *(const f16x8*)(htile + il * 1024 + (inr ^ ((il & 7) << 4)));
    }

    // ---- gates = [x_t; h_{t-1}] @ Wcat^T  (4 indep accum chains; B-frags from LDS) ----
    f32x4 ac0 = {0.f,0.f,0.f,0.f}, ac1 = {0.f,0.f,0.f,0.f};
    f32x4 ac2 = {0.f,0.f,0.f,0.f}, ac3 = {0.f,0.f,0.f,0.f};
#pragma unroll
    for (int kk = 0; kk < 16; kk += 4) {
      ac0 = MFMA(ax[kk + 0], wbase[(kk + 0) * 64], ac0);
      ac1 = MFMA(ax[kk + 1], wbase[(kk + 1) * 64], ac1);
      ac2 = MFMA(ax[kk + 2], wbase[(kk + 2) * 64], ac2);
      ac3 = MFMA(ax[kk + 3], wbase[(kk + 3) * 64], ac3);
    }
#pragma unroll
    for (int kk = 0; kk < 16; kk += 4) {
      ac0 = MFMA(fh[kk + 0], wbase[(16 + kk + 0) * 64], ac0);
      ac1 = MFMA(fh[kk + 1], wbase[(16 + kk + 1) * 64], ac1);
      ac2 = MFMA(fh[kk + 2], wbase[(16 + kk + 2) * 64], ac2);
      ac3 = MFMA(fh[kk + 3], wbase[(16 + kk + 3) * 64], ac3);
    }

    // D-frag: col = lane&15, row = (lane>>4)*4 + r  (m89-verified, dtype-independent)
#pragma unroll
    for (int r = 0; r < 4; ++r)
      glds[kg * 4 + r][wv * 16 + il] = ac0[r] + ac1[r] + ac2[r] + ac3[r];
    __syncthreads();   // B3: glds ready

    // ---- LSTM cell (gate order i,f,g,o) ----
    float gi = glds[bl_e][ 0 + i_e] + bi_;
    float gf = glds[bl_e][16 + i_e] + bf_;
    float gg = glds[bl_e][32 + i_e] + bg_;
    float go = glds[bl_e][48 + i_e] + bo_;
    float si = fsig(gi), sf = fsig(gf), so = fsig(go);
    float tg = ftanh_(gg);
    cst = sf * cst + si * tg;
    float hv = so * ftanh_(cst);

    // publish h(t) (parity t&1), LLC-coherent
    unsigned short hbits = __half_as_ushort(__float2half(hv));
    unsigned short* hp = (unsigned short*)(hb + (size_t)(t & 1) * BB * HH + (size_t)b_e * HH + col_e);
    __hip_atomic_store(hp, hbits, __ATOMIC_RELAXED, __HIP_MEMORY_SCOPE_AGENT);

    __syncthreads();   // B4: drains h publish stores (vmcnt 0) before the flag release
    if (tid == 0)
      __hip_atomic_store(&fl[cg], t + 2, __ATOMIC_RELAXED, __HIP_MEMORY_SCOPE_AGENT);

    // ---- HBM out store AFTER the flag: off the inter-block critical path ----
    if (dir == 0) {
      out[((size_t)b_e * TT + t) * (2 * HH) + col_e] = hv;
    } else {
      int td = len_e - 1 - t; if (td < 0) td += TT;
      out[((size_t)b_e * TT + td) * (2 * HH) + HH + col_e] = hv;
    }
  }
}

extern "C" void kernel_launch(void* const* d_in, const int* in_sizes, int n_in,
                              void* d_out, int out_size, void* d_ws, size_t ws_size,
                              hipStream_t stream) {
  const float* x    = (const float*)d_in[0];
  const float* mask = (const float*)d_in[1];
  const float* h0   = (const float*)d_in[2];
  const float* c0   = (const float*)d_in[3];
  const float* Wi_f = (const float*)d_in[4];
  const float* Wh_f = (const float*)d_in[5];
  const float* b_f  = (const float*)d_in[6];
  const float* Wi_b = (const float*)d_in[7];
  const float* Wh_b = (const float*)d_in[8];
  const float* b_b  = (const float*)d_in[9];
  float* out = (float*)d_out;

  char* ws = (char*)d_ws;
  int*    flags = (int*)(ws + WS_FLAGS);
  int*    lens  = (int*)(ws + WS_LENS);
  __half* hbuf  = (__half*)(ws + WS_HBUF);

  // zero the sync flags every call (harness poisons ws once with 0xAA)
  hipMemsetAsync(ws, 0, 4096, stream);

  hipLaunchKernelGGL(len_kernel, dim3(1), dim3(64), 0, stream, mask, lens);

  // opt-in to >64KB dynamic LDS (idempotent, not a stream op -> graph-capture safe)
  hipFuncSetAttribute((const void*)bilstm_kernel,
                      hipFuncAttributeMaxDynamicSharedMemorySize, LDS_TOTAL);

  // Plain (non-cooperative) launch: 148KB LDS -> 1 block/CU, grid == CU count,
  // so all 256 blocks are co-resident at dispatch; sync is hand-rolled flags.
  hipLaunchKernelGGL(bilstm_kernel, dim3(256), dim3(256), LDS_TOTAL, stream,
                     x, lens, h0, c0, Wi_f, Wh_f, b_f, Wi_b, Wh_b, b_b,
                     out, hbuf, flags);
}